// Round 3
// baseline (183.343 us; speedup 1.0000x reference)
//
#include <hip/hip_runtime.h>

#define HW 64
#define NB 4
#define CH 256

typedef __attribute__((address_space(1))) const void* gptr_t;
typedef __attribute__((address_space(3))) void* lptr_t;
typedef __attribute__((ext_vector_type(8))) short bf8v;   // 8 bf16 bit-patterns
typedef __attribute__((ext_vector_type(4))) float f32x4;

__device__ __forceinline__ void gll16(const void* g, void* l) {
  __builtin_amdgcn_global_load_lds((gptr_t)g, (lptr_t)l, 16, 0, 0);
}
__device__ __forceinline__ ushort f2b(float f) {
  union { float f; uint u; } v; v.f = f;
  uint r = v.u + 0x7FFF + ((v.u >> 16) & 1);
  return (ushort)(r >> 16);
}
__device__ __forceinline__ float b2f(ushort b) {
  union { uint u; float f; } v; v.u = ((uint)b) << 16;
  return v.f;
}

// ---------------------------------------------------------------------------
// pack_x: x NCHW f32 -> xpad [4][66][66][256] bf16 (interior)
// ---------------------------------------------------------------------------
__global__ __launch_bounds__(256) void pack_x_k(
    const float* __restrict__ x, ushort* __restrict__ xpad)
{
  __shared__ float tile[64][261];
  const int t = threadIdx.x, b = blockIdx.x >> 6, i = blockIdx.x & 63;
  const int wave = t >> 6, l = t & 63;
  const float* src = x + (size_t)b * CH * 4096 + (size_t)i * 64;
  for (int cc = 0; cc < 64; ++cc) {
    const int c = cc * 4 + wave;
    tile[l][c] = src[(size_t)c * 4096 + l];
  }
  __syncthreads();
  const int j = t >> 2, cq = t & 3;
  ushort* xpo = xpad + ((size_t)b * 4356 + (i + 1) * 66 + (j + 1)) * 256;
  #pragma unroll
  for (int q = 0; q < 16; ++q) {
    const int c = cq * 64 + q * 4;
    const float4 v = *(const float4*)&tile[j][c];
    ushort4 s; s.x = f2b(v.x); s.y = f2b(v.y); s.z = f2b(v.z); s.w = f2b(v.w);
    *(ushort4*)&xpo[c] = s;
  }
}

// ---------------------------------------------------------------------------
// pack_w: w1/w2/dw -> [cb8][tap9][o256][kc4][8] bf16 ; pw -> [cb][tap][32][kc][8]
// ---------------------------------------------------------------------------
__global__ __launch_bounds__(256) void pack_w_k(
    const float* __restrict__ w1, const float* __restrict__ w2,
    const float* __restrict__ dw, const float* __restrict__ pw,
    const float* __restrict__ pb,
    ushort* __restrict__ wpk1, ushort* __restrict__ wpk2,
    ushort* __restrict__ dwpk, ushort* __restrict__ wpkO, float* __restrict__ pbias)
{
  const int id = blockIdx.x * 256 + threadIdx.x;
  if (id < 3 * 73728) {
    const int tsel = id / 73728, r = id % 73728;
    const int kc = r & 3, o = (r >> 2) & 255, ct = r >> 10;
    const int cb = ct / 9, tap = ct % 9;
    const float* w = (tsel == 0) ? w1 : (tsel == 1) ? w2 : dw;
    const float* s = w + ((size_t)o * CH + cb * 32 + kc * 8) * 9 + tap;
    ushort* d = ((tsel == 0) ? wpk1 : (tsel == 1) ? wpk2 : dwpk) + (size_t)r * 8;
    #pragma unroll
    for (int j = 0; j < 8; ++j) d[j] = f2b(s[j * 9]);
  } else if (id < 3 * 73728 + 9216) {
    const int r = id - 3 * 73728;
    const int kc = r & 3, o = (r >> 2) & 31, ct = r >> 7;
    const int cb = ct / 9, tap = ct % 9;
    ushort* d = wpkO + (size_t)r * 8;
    if (o < 18) {
      const float* s = pw + ((size_t)o * CH + cb * 32 + kc * 8) * 9 + tap;
      #pragma unroll
      for (int j = 0; j < 8; ++j) d[j] = f2b(s[j * 9]);
    } else {
      #pragma unroll
      for (int j = 0; j < 8; ++j) d[j] = 0;
    }
  }
  if (id < 32) pbias[id] = (id < 18) ? pb[id] : 0.f;
}

// ---------------------------------------------------------------------------
// Implicit-GEMM 3x3 conv via MFMA, B-fragments loaded direct from L2.
// OTOT=256: block = (b, row i, ot of 4); 4 waves: wave = (o 32-slice, px half).
// OTOT=32 (offset conv): block = (b, i); 4 waves = px quarters, shared 32 o.
// LDS: double-buffered 3-row x 66-px x 32-ch patch (2 x 12672 B).
// ---------------------------------------------------------------------------
template<int OTOT, int OUTMODE>
__global__ __launch_bounds__(256, 4) void conv_mfma(
    const ushort* __restrict__ apad, const ushort* __restrict__ wpk,
    const float* __restrict__ bias, const float* __restrict__ xres,
    void* __restrict__ outp)
{
  __shared__ __align__(16) ushort patch[2][6336];
  const int t = threadIdx.x, wave = t >> 6, l = t & 63;
  const int ot  = (OTOT == 256) ? (blockIdx.x >> 8) : 0;
  const int rem = blockIdx.x & 255;
  const int b = rem >> 6, i = rem & 63;
  const int ln = l & 15, kc8 = (l >> 4) * 8;

  constexpr int FO = 2;
  constexpr int FP = (OTOT == 256) ? 2 : 1;
  const int oS  = (OTOT == 256) ? (ot * 64 + (wave >> 1) * 32) : 0;
  const int pxB = (OTOT == 256) ? ((wave & 1) * 32) : (wave * 16);

  const ushort* rowbase = apad + ((size_t)(b * 66 + i) * 66) * 256;

  f32x4 acc[FO][FP];
  #pragma unroll
  for (int a = 0; a < FO; ++a)
    #pragma unroll
    for (int d = 0; d < FP; ++d) acc[a][d] = (f32x4){0.f, 0.f, 0.f, 0.f};

  #define STAGE(buf, cb)                                                        \
    _Pragma("unroll")                                                           \
    for (int it = 0; it < 4; ++it) {                                            \
      const int e = t + it * 256;                                               \
      if (it < 3 || t < 24) {                                                   \
        const int r = e / 264, u = e - r * 264;                                 \
        const ushort* s = rowbase + ((size_t)(r * 66) + (u >> 2)) * 256         \
                          + (cb) * 32 + (u & 3) * 8;                            \
        gll16(s, (ushort*)&patch[buf][0] + (size_t)e * 8);                      \
      }                                                                         \
    }

  STAGE(0, 0)
  for (int cb = 0; cb < 8; ++cb) {
    __syncthreads();                           // patch[cb&1] ready
    if (cb < 7) { STAGE((cb + 1) & 1, cb + 1) }  // overlap next stage with MFMA
    const ushort* pbuf = &patch[cb & 1][0];
    #pragma unroll
    for (int tap = 0; tap < 9; ++tap) {
      const int ky = tap / 3, kx = tap % 3;
      bf8v wf[FO], pf[FP];
      #pragma unroll
      for (int fo = 0; fo < FO; ++fo)
        wf[fo] = *(const bf8v*)&wpk[((size_t)((cb * 9 + tap) * OTOT) + oS + fo * 16 + ln) * 32 + kc8];
      #pragma unroll
      for (int fp = 0; fp < FP; ++fp) {
        const int px = pxB + fp * 16 + ln;
        pf[fp] = *(const bf8v*)&pbuf[ky * 2112 + (px + kx) * 32 + kc8];
      }
      #pragma unroll
      for (int fo = 0; fo < FO; ++fo)
        #pragma unroll
        for (int fp = 0; fp < FP; ++fp)
          acc[fo][fp] = __builtin_amdgcn_mfma_f32_16x16x32_bf16(wf[fo], pf[fp], acc[fo][fp], 0, 0, 0);
    }
  }
  #undef STAGE

  #pragma unroll
  for (int fo = 0; fo < FO; ++fo) {
    #pragma unroll
    for (int fp = 0; fp < FP; ++fp) {
      const f32x4 a = acc[fo][fp];
      const int o = oS + fo * 16 + (l >> 4) * 4;
      const int j = pxB + fp * 16 + ln;
      const float4 bv = *(const float4*)&bias[o];
      float v0 = a[0] + bv.x, v1 = a[1] + bv.y, v2 = a[2] + bv.z, v3 = a[3] + bv.w;
      if (OUTMODE == 0) {
        const size_t xb = (((size_t)b * CH + o) * HW + i) * HW + j;
        v0 = fmaxf(v0, 0.f) + xres[xb];
        v1 = fmaxf(v1, 0.f) + xres[xb + 4096];
        v2 = fmaxf(v2, 0.f) + xres[xb + 8192];
        v3 = fmaxf(v3, 0.f) + xres[xb + 12288];
      }
      if (OUTMODE == 2) {
        float* op = (float*)outp + ((size_t)b * 4096 + i * 64 + j) * 32 + o;
        float4 r; r.x = v0; r.y = v1; r.z = v2; r.w = v3;
        *(float4*)op = r;
      } else {
        ushort* op = (ushort*)outp + ((size_t)b * 4356 + (i + 1) * 66 + (j + 1)) * 256 + o;
        ushort4 s; s.x = f2b(v0); s.y = f2b(v1); s.z = f2b(v2); s.w = f2b(v3);
        *(ushort4*)op = s;
      }
    }
  }
}

// ---------------------------------------------------------------------------
// Deform GEMM + residual, fused bilinear table. block = (b, row i), 1024 thr
// = 16 waves: wave = (o 32-slice x px 32-half). B direct from L2 to regs.
// ---------------------------------------------------------------------------
__global__ __launch_bounds__(1024, 4) void deform_mfma(
    const ushort* __restrict__ res2pad, const float* __restrict__ offs,
    const ushort* __restrict__ dwpk, const float* __restrict__ x,
    float* __restrict__ out)
{
  __shared__ __align__(16) ushort samp[18432];     // (tap*64+px)*32 + c
  __shared__ __align__(16) int    tbl_i[576 * 4];
  __shared__ __align__(16) float  tbl_w[576 * 4];

  const int t = threadIdx.x, wave = t >> 6, l = t & 63;
  const int b = blockIdx.x >> 6, i = blockIdx.x & 63;
  const int ln = l & 15, kc8 = (l >> 4) * 8;

  if (t < 576) {
    const int n = t >> 6, j = t & 63;
    const int ki = n / 3, kj = n % 3;
    const float offr = offs[((size_t)b * 4096 + i * 64 + j) * 32 + n];
    const float offc = offs[((size_t)b * 4096 + i * 64 + j) * 32 + 9 + n];
    const float prow = offr + (float)(ki - 1) + (float)(i + 1);
    const float pcol = offc + (float)(kj - 1) + (float)(j + 1);
    const float fx = floorf(prow), fy = floorf(pcol);
    const float qlx = fminf(fmaxf(fx, 0.f), 65.f);
    const float qly = fminf(fmaxf(fy, 0.f), 65.f);
    const float qrx = fminf(fmaxf(fx + 1.f, 0.f), 65.f);
    const float qry = fminf(fmaxf(fy + 1.f, 0.f), 65.f);
    const float pr  = fminf(fmaxf(prow, 0.f), 65.f);
    const float pc  = fminf(fmaxf(pcol, 0.f), 65.f);
    tbl_i[t * 4 + 0] = (int)qlx * 66 + (int)qly;
    tbl_i[t * 4 + 1] = (int)qrx * 66 + (int)qry;
    tbl_i[t * 4 + 2] = (int)qlx * 66 + (int)qry;
    tbl_i[t * 4 + 3] = (int)qrx * 66 + (int)qly;
    tbl_w[t * 4 + 0] = (1.f + qlx - pr) * (1.f + qly - pc);
    tbl_w[t * 4 + 1] = (1.f - qrx + pr) * (1.f - qry + pc);
    tbl_w[t * 4 + 2] = (1.f + qlx - pr) * (1.f - qry + pc);
    tbl_w[t * 4 + 3] = (1.f - qrx + pr) * (1.f + qly - pc);
  }

  f32x4 acc[2][2];
  #pragma unroll
  for (int a = 0; a < 2; ++a) { acc[a][0] = (f32x4){0,0,0,0}; acc[a][1] = (f32x4){0,0,0,0}; }

  const ushort* res2b = res2pad + (size_t)b * 4356 * 256;
  const int oS  = (wave >> 1) * 32;
  const int pxB = (wave & 1) * 32;

  __syncthreads();

  for (int cb = 0; cb < 8; ++cb) {
    #pragma unroll
    for (int k = 0; k < 3; ++k) {
      const int u = t + k * 1024;
      if (k < 2 || t < 256) {
        const int e = u >> 2, i16 = u & 3;
        const int4 iv = *(const int4*)&tbl_i[e * 4];
        const ushort* base = res2b + cb * 32 + i16 * 8;
        const bf8v c0 = *(const bf8v*)(base + (size_t)iv.x * 256);
        const bf8v c1 = *(const bf8v*)(base + (size_t)iv.y * 256);
        const bf8v c2 = *(const bf8v*)(base + (size_t)iv.z * 256);
        const bf8v c3 = *(const bf8v*)(base + (size_t)iv.w * 256);
        const float4 gv = *(const float4*)&tbl_w[e * 4];
        bf8v ob;
        #pragma unroll
        for (int jj = 0; jj < 8; ++jj) {
          const float s = gv.x * b2f((ushort)c0[jj]) + gv.y * b2f((ushort)c1[jj])
                        + gv.z * b2f((ushort)c2[jj]) + gv.w * b2f((ushort)c3[jj]);
          ob[jj] = (short)f2b(s);
        }
        *(bf8v*)&samp[(size_t)u * 8] = ob;
      }
    }
    __syncthreads();

    __builtin_amdgcn_s_setprio(1);
    #pragma unroll
    for (int tap = 0; tap < 9; ++tap) {
      bf8v af[2], bf[2];
      #pragma unroll
      for (int fp = 0; fp < 2; ++fp)
        af[fp] = *(const bf8v*)&samp[(tap * 64 + pxB + fp * 16 + ln) * 32 + kc8];
      #pragma unroll
      for (int fo = 0; fo < 2; ++fo)
        bf[fo] = *(const bf8v*)&dwpk[((size_t)(cb * 9 + tap) * 256 + oS + fo * 16 + ln) * 32 + kc8];
      #pragma unroll
      for (int fp = 0; fp < 2; ++fp)
        #pragma unroll
        for (int fo = 0; fo < 2; ++fo)
          acc[fp][fo] = __builtin_amdgcn_mfma_f32_16x16x32_bf16(af[fp], bf[fo], acc[fp][fo], 0, 0, 0);
    }
    __builtin_amdgcn_s_setprio(0);
    __syncthreads();
  }

  #pragma unroll
  for (int fp = 0; fp < 2; ++fp) {
    #pragma unroll
    for (int fo = 0; fo < 2; ++fo) {
      const f32x4 a = acc[fp][fo];
      const int o = oS + fo * 16 + ln;
      const int j0 = pxB + fp * 16 + (l >> 4) * 4;
      const size_t base = (((size_t)b * CH + o) * HW + i) * HW + j0;
      const float4 xv = *(const float4*)&x[base];
      float4 r; r.x = a[0] + xv.x; r.y = a[1] + xv.y; r.z = a[2] + xv.z; r.w = a[3] + xv.w;
      *(float4*)&out[base] = r;
    }
  }
}

// ---------------------------------------------------------------------------
extern "C" void kernel_launch(void* const* d_in, const int* in_sizes, int n_in,
                              void* d_out, int out_size, void* d_ws, size_t ws_size,
                              hipStream_t stream) {
  (void)in_sizes; (void)n_in; (void)out_size; (void)ws_size;
  const float* x  = (const float*)d_in[0];
  const float* w1 = (const float*)d_in[1];
  const float* b1 = (const float*)d_in[2];
  const float* w2 = (const float*)d_in[3];
  const float* b2 = (const float*)d_in[4];
  const float* pw = (const float*)d_in[5];
  const float* pb = (const float*)d_in[6];
  const float* dw = (const float*)d_in[7];
  float* out = (float*)d_out;

  char* w = (char*)d_ws;
  size_t off = 0;
  auto carve = [&](size_t bytes) { char* p = w + off; off += (bytes + 255) & ~(size_t)255; return p; };
  ushort* xpad  = (ushort*)carve(8929280);   // 4*4356*256*2 + slack
  ushort* res1  = (ushort*)carve(8929280);
  ushort* res2  = (ushort*)carve(8929280);
  ushort* wpk1  = (ushort*)carve(1179648);
  ushort* wpk2  = (ushort*)carve(1179648);
  ushort* wpkO  = (ushort*)carve(147456);
  ushort* dwpk  = (ushort*)carve(1179648);
  float*  pbias = (float*) carve(256);
  float*  offs  = (float*) carve(2097152);

  hipMemsetAsync(xpad, 0, 8929280, stream);
  hipMemsetAsync(res1, 0, 8929280, stream);
  hipMemsetAsync(res2, 0, 8929280, stream);

  pack_w_k<<<900, 256, 0, stream>>>(w1, w2, dw, pw, pb, wpk1, wpk2, dwpk, wpkO, pbias);
  pack_x_k<<<256, 256, 0, stream>>>(x, xpad);
  conv_mfma<256, 0><<<1024, 256, 0, stream>>>(xpad, wpk1, b1, x, res1);
  conv_mfma<256, 1><<<1024, 256, 0, stream>>>(res1, wpk2, b2, nullptr, res2);
  conv_mfma<32, 2><<<256, 256, 0, stream>>>(res2, wpkO, pbias, nullptr, offs);
  deform_mfma<<<NB * HW, 1024, 0, stream>>>(res2, offs, dwpk, x, out);
}

// Round 4
// 140.427 us; speedup vs baseline: 1.3056x; 1.3056x over previous
//
#include <hip/hip_runtime.h>

#define HW 64
#define NB 4
#define CH 256

typedef __attribute__((address_space(1))) const void* gptr_t;
typedef __attribute__((address_space(3))) void* lptr_t;
typedef __attribute__((ext_vector_type(8))) short bf8v;   // 8 bf16 bit-patterns
typedef __attribute__((ext_vector_type(4))) float f32x4;

__device__ __forceinline__ void gll16(const void* g, void* l) {
  __builtin_amdgcn_global_load_lds((gptr_t)g, (lptr_t)l, 16, 0, 0);
}
__device__ __forceinline__ ushort f2b(float f) {
  union { float f; uint u; } v; v.f = f;
  uint r = v.u + 0x7FFF + ((v.u >> 16) & 1);
  return (ushort)(r >> 16);
}
__device__ __forceinline__ float b2f(ushort b) {
  union { uint u; float f; } v; v.u = ((uint)b) << 16;
  return v.f;
}

// ---------------------------------------------------------------------------
// zero_borders: zero the 260 border pixels (x 256 ch) of each padded buffer
// grid = 3 bufs x 4 batches
// ---------------------------------------------------------------------------
__global__ __launch_bounds__(256) void zero_borders_k(
    ushort* __restrict__ xpad, ushort* __restrict__ res1, ushort* __restrict__ res2)
{
  const int buf = blockIdx.x >> 2, b = blockIdx.x & 3;
  ushort* base = (buf == 0 ? xpad : buf == 1 ? res1 : res2) + (size_t)b * 4356 * 256;
  uint4 z; z.x = 0; z.y = 0; z.z = 0; z.w = 0;
  for (int u = threadIdx.x; u < 260 * 32; u += 256) {
    const int p = u >> 5, k = u & 31;
    int r, cc;
    if (p < 66)       { r = 0;       cc = p; }
    else if (p < 132) { r = 65;      cc = p - 66; }
    else if (p < 196) { r = p - 131; cc = 0; }
    else              { r = p - 195; cc = 65; }
    *(uint4*)&base[((size_t)r * 66 + cc) * 256 + k * 8] = z;
  }
}

// ---------------------------------------------------------------------------
// pack_x: x NCHW f32 -> xpad [4][66][66][256] bf16 (interior)
// ---------------------------------------------------------------------------
__global__ __launch_bounds__(256) void pack_x_k(
    const float* __restrict__ x, ushort* __restrict__ xpad)
{
  __shared__ float tile[64][261];
  const int t = threadIdx.x, b = blockIdx.x >> 6, i = blockIdx.x & 63;
  const int wave = t >> 6, l = t & 63;
  const float* src = x + (size_t)b * CH * 4096 + (size_t)i * 64;
  for (int cc = 0; cc < 64; ++cc) {
    const int c = cc * 4 + wave;
    tile[l][c] = src[(size_t)c * 4096 + l];
  }
  __syncthreads();
  const int c0 = (t & 31) * 8;
  #pragma unroll
  for (int jj = 0; jj < 8; ++jj) {
    const int j = (t >> 5) + jj * 8;
    const float4 v0 = *(const float4*)&tile[j][c0];
    const float4 v1 = *(const float4*)&tile[j][c0 + 4];
    uint4 o;
    o.x = (uint)f2b(v0.x) | ((uint)f2b(v0.y) << 16);
    o.y = (uint)f2b(v0.z) | ((uint)f2b(v0.w) << 16);
    o.z = (uint)f2b(v1.x) | ((uint)f2b(v1.y) << 16);
    o.w = (uint)f2b(v1.z) | ((uint)f2b(v1.w) << 16);
    *(uint4*)&xpad[((size_t)b * 4356 + (i + 1) * 66 + (j + 1)) * 256 + c0] = o;
  }
}

// ---------------------------------------------------------------------------
// pack_w: w1/w2/dw -> [cb8][tap9][o256][kc4][8] bf16 ; pw -> [cb][tap][32][kc][8]
// ---------------------------------------------------------------------------
__global__ __launch_bounds__(256) void pack_w_k(
    const float* __restrict__ w1, const float* __restrict__ w2,
    const float* __restrict__ dw, const float* __restrict__ pw,
    const float* __restrict__ pb,
    ushort* __restrict__ wpk1, ushort* __restrict__ wpk2,
    ushort* __restrict__ dwpk, ushort* __restrict__ wpkO, float* __restrict__ pbias)
{
  const int id = blockIdx.x * 256 + threadIdx.x;
  if (id < 3 * 73728) {
    const int tsel = id / 73728, r = id % 73728;
    const int kc = r & 3, o = (r >> 2) & 255, ct = r >> 10;
    const int cb = ct / 9, tap = ct % 9;
    const float* w = (tsel == 0) ? w1 : (tsel == 1) ? w2 : dw;
    const float* s = w + ((size_t)o * CH + cb * 32 + kc * 8) * 9 + tap;
    ushort* d = ((tsel == 0) ? wpk1 : (tsel == 1) ? wpk2 : dwpk) + (size_t)r * 8;
    #pragma unroll
    for (int j = 0; j < 8; ++j) d[j] = f2b(s[j * 9]);
  } else if (id < 3 * 73728 + 9216) {
    const int r = id - 3 * 73728;
    const int kc = r & 3, o = (r >> 2) & 31, ct = r >> 7;
    const int cb = ct / 9, tap = ct % 9;
    ushort* d = wpkO + (size_t)r * 8;
    if (o < 18) {
      const float* s = pw + ((size_t)o * CH + cb * 32 + kc * 8) * 9 + tap;
      #pragma unroll
      for (int j = 0; j < 8; ++j) d[j] = f2b(s[j * 9]);
    } else {
      #pragma unroll
      for (int j = 0; j < 8; ++j) d[j] = 0;
    }
  }
  if (id < 32) pbias[id] = (id < 18) ? pb[id] : 0.f;
}

// ---------------------------------------------------------------------------
// Implicit-GEMM 3x3 conv via MFMA, B (weights) loaded L2->regs, hoisted per cb
// BEFORE patch prefetch so per-tap vmcnt waits never drain the prefetch.
// OTOT=256: block = (b,i,ot of 4); 4 waves = 4 o-slices of 16; FP=4 (full row).
// OTOT=32 (offset conv): 4 waves = px quarters; FO=2 (32 o), FP=1.
// ---------------------------------------------------------------------------
template<int OTOT, int OUTMODE>
__global__ __launch_bounds__(256, 4) void conv_mfma(
    const ushort* __restrict__ apad, const ushort* __restrict__ wpk,
    const float* __restrict__ bias, const float* __restrict__ xres,
    void* __restrict__ outp)
{
  __shared__ __align__(16) ushort patch[2][6336];
  const int t = threadIdx.x, wave = t >> 6, l = t & 63;
  const int ot  = (OTOT == 256) ? (blockIdx.x >> 8) : 0;
  const int rem = blockIdx.x & 255;
  const int b = rem >> 6, i = rem & 63;
  const int ln = l & 15, kc8 = (l >> 4) * 8;

  constexpr int FO = (OTOT == 256) ? 1 : 2;
  constexpr int FP = (OTOT == 256) ? 4 : 1;
  const int oS  = (OTOT == 256) ? (ot * 64 + wave * 16) : 0;
  const int pxB = (OTOT == 256) ? 0 : (wave * 16);

  const ushort* rowbase = apad + ((size_t)(b * 66 + i) * 66) * 256;

  f32x4 acc[FO][FP];
  #pragma unroll
  for (int a = 0; a < FO; ++a)
    #pragma unroll
    for (int d = 0; d < FP; ++d) acc[a][d] = (f32x4){0.f, 0.f, 0.f, 0.f};

  #define STAGE(buf, cb)                                                        \
    _Pragma("unroll")                                                           \
    for (int it = 0; it < 4; ++it) {                                            \
      const int e = t + it * 256;                                               \
      if (it < 3 || t < 24) {                                                   \
        const int r = e / 264, u = e - r * 264;                                 \
        const ushort* s = rowbase + ((size_t)(r * 66) + (u >> 2)) * 256         \
                          + (cb) * 32 + (u & 3) * 8;                            \
        gll16(s, (ushort*)&patch[buf][0] + (size_t)e * 8);                      \
      }                                                                         \
    }

  STAGE(0, 0)
  for (int cb = 0; cb < 8; ++cb) {
    __syncthreads();                           // patch[cb&1] ready
    // hoist all 9 taps' weight fragments FIRST (oldest vmcnt entries)
    bf8v wfr[9][FO];
    #pragma unroll
    for (int tap = 0; tap < 9; ++tap)
      #pragma unroll
      for (int fo = 0; fo < FO; ++fo)
        wfr[tap][fo] = *(const bf8v*)&wpk[((size_t)((cb * 9 + tap) * OTOT) + oS + fo * 16 + ln) * 32 + kc8];
    if (cb < 7) { STAGE((cb + 1) & 1, cb + 1) }  // prefetch stays in flight
    const ushort* pbuf = &patch[cb & 1][0];
    __builtin_amdgcn_s_setprio(1);
    #pragma unroll
    for (int tap = 0; tap < 9; ++tap) {
      const int ky = tap / 3, kx = tap % 3;
      bf8v pf[FP];
      #pragma unroll
      for (int fp = 0; fp < FP; ++fp) {
        const int px = pxB + fp * 16 + ln;
        pf[fp] = *(const bf8v*)&pbuf[ky * 2112 + (px + kx) * 32 + kc8];
      }
      #pragma unroll
      for (int fo = 0; fo < FO; ++fo)
        #pragma unroll
        for (int fp = 0; fp < FP; ++fp)
          acc[fo][fp] = __builtin_amdgcn_mfma_f32_16x16x32_bf16(wfr[tap][fo], pf[fp], acc[fo][fp], 0, 0, 0);
    }
    __builtin_amdgcn_s_setprio(0);
  }
  #undef STAGE

  #pragma unroll
  for (int fo = 0; fo < FO; ++fo) {
    #pragma unroll
    for (int fp = 0; fp < FP; ++fp) {
      const f32x4 a = acc[fo][fp];
      const int o = oS + fo * 16 + (l >> 4) * 4;
      const int j = pxB + fp * 16 + ln;
      const float4 bv = *(const float4*)&bias[o];
      float v0 = a[0] + bv.x, v1 = a[1] + bv.y, v2 = a[2] + bv.z, v3 = a[3] + bv.w;
      if (OUTMODE == 0) {
        const size_t xb = (((size_t)b * CH + o) * HW + i) * HW + j;
        v0 = fmaxf(v0, 0.f) + xres[xb];
        v1 = fmaxf(v1, 0.f) + xres[xb + 4096];
        v2 = fmaxf(v2, 0.f) + xres[xb + 8192];
        v3 = fmaxf(v3, 0.f) + xres[xb + 12288];
      }
      if (OUTMODE == 2) {
        float* op = (float*)outp + ((size_t)b * 4096 + i * 64 + j) * 32 + o;
        float4 r; r.x = v0; r.y = v1; r.z = v2; r.w = v3;
        *(float4*)op = r;
      } else {
        ushort* op = (ushort*)outp + ((size_t)b * 4356 + (i + 1) * 66 + (j + 1)) * 256 + o;
        ushort4 s; s.x = f2b(v0); s.y = f2b(v1); s.z = f2b(v2); s.w = f2b(v3);
        *(ushort4*)op = s;
      }
    }
  }
}

// ---------------------------------------------------------------------------
// Deform GEMM + residual, fused bilinear table, software-pipelined sampling.
// block = (b, row i), 1024 thr = 16 waves = 16 o-slices of 16; FP=4 per wave.
// Per cb: [bfr 9-tap weight loads] [gather-issue cb+1 -> regs] [MFMA cb]
//         [bilinear-finish cb+1 -> samp dbuf] [tail units] [barrier].
// ---------------------------------------------------------------------------
__global__ __launch_bounds__(1024, 4) void deform_mfma(
    const ushort* __restrict__ res2pad, const float* __restrict__ offs,
    const ushort* __restrict__ dwpk, const float* __restrict__ x,
    float* __restrict__ out)
{
  __shared__ __align__(16) ushort samp[2][18432];   // [(tap*64+px)*32 + c]
  __shared__ __align__(16) int    tbl_i[576 * 4];
  __shared__ __align__(16) float  tbl_w[576 * 4];

  const int t = threadIdx.x, wave = t >> 6, l = t & 63;
  const int b = blockIdx.x >> 6, i = blockIdx.x & 63;
  const int ln = l & 15, kc8 = (l >> 4) * 8;
  const int oS = wave * 16;

  if (t < 576) {
    const int n = t >> 6, j = t & 63;
    const int ki = n / 3, kj = n % 3;
    const float offr = offs[((size_t)b * 4096 + i * 64 + j) * 32 + n];
    const float offc = offs[((size_t)b * 4096 + i * 64 + j) * 32 + 9 + n];
    const float prow = offr + (float)(ki - 1) + (float)(i + 1);
    const float pcol = offc + (float)(kj - 1) + (float)(j + 1);
    const float fx = floorf(prow), fy = floorf(pcol);
    const float qlx = fminf(fmaxf(fx, 0.f), 65.f);
    const float qly = fminf(fmaxf(fy, 0.f), 65.f);
    const float qrx = fminf(fmaxf(fx + 1.f, 0.f), 65.f);
    const float qry = fminf(fmaxf(fy + 1.f, 0.f), 65.f);
    const float pr  = fminf(fmaxf(prow, 0.f), 65.f);
    const float pc  = fminf(fmaxf(pcol, 0.f), 65.f);
    tbl_i[t * 4 + 0] = (int)qlx * 66 + (int)qly;
    tbl_i[t * 4 + 1] = (int)qrx * 66 + (int)qry;
    tbl_i[t * 4 + 2] = (int)qlx * 66 + (int)qry;
    tbl_i[t * 4 + 3] = (int)qrx * 66 + (int)qly;
    tbl_w[t * 4 + 0] = (1.f + qlx - pr) * (1.f + qly - pc);
    tbl_w[t * 4 + 1] = (1.f - qrx + pr) * (1.f - qry + pc);
    tbl_w[t * 4 + 2] = (1.f + qlx - pr) * (1.f - qry + pc);
    tbl_w[t * 4 + 3] = (1.f - qrx + pr) * (1.f + qly - pc);
  }

  f32x4 acc[4];
  #pragma unroll
  for (int a = 0; a < 4; ++a) acc[a] = (f32x4){0.f, 0.f, 0.f, 0.f};

  const ushort* res2b = res2pad + (size_t)b * 4356 * 256;
  __syncthreads();   // table ready

  // sample one unit u for channel block cb directly into samp[buf]
  #define SAMPLE_DIRECT(u_, cb_, buf_) {                                        \
    const int e = (u_) >> 2, i16 = (u_) & 3;                                    \
    const int4 iv = *(const int4*)&tbl_i[e * 4];                                \
    const ushort* base = res2b + (cb_) * 32 + i16 * 8;                          \
    const bf8v c0 = *(const bf8v*)(base + (size_t)iv.x * 256);                  \
    const bf8v c1 = *(const bf8v*)(base + (size_t)iv.y * 256);                  \
    const bf8v c2 = *(const bf8v*)(base + (size_t)iv.z * 256);                  \
    const bf8v c3 = *(const bf8v*)(base + (size_t)iv.w * 256);                  \
    const float4 gv = *(const float4*)&tbl_w[e * 4];                            \
    bf8v ob;                                                                    \
    _Pragma("unroll")                                                           \
    for (int jj = 0; jj < 8; ++jj) {                                            \
      const float s = gv.x * b2f((ushort)c0[jj]) + gv.y * b2f((ushort)c1[jj])   \
                    + gv.z * b2f((ushort)c2[jj]) + gv.w * b2f((ushort)c3[jj]);  \
      ob[jj] = (short)f2b(s);                                                   \
    }                                                                           \
    *(bf8v*)&samp[buf_][(size_t)(u_) * 8] = ob;                                 \
  }

  // prologue: fully sample cb=0 into samp[0]
  #pragma unroll
  for (int k = 0; k < 3; ++k) {
    if (k < 2 || t < 256) {
      const int u = t + k * 1024;
      SAMPLE_DIRECT(u, 0, 0)
    }
  }
  __syncthreads();

  bf8v cr[2][4];
  for (int cb = 0; cb < 8; ++cb) {
    // 1) hoist this cb's 9 weight fragments (oldest vmcnt entries)
    bf8v bfr[9];
    #pragma unroll
    for (int tap = 0; tap < 9; ++tap)
      bfr[tap] = *(const bf8v*)&dwpk[((size_t)(cb * 9 + tap) * 256 + oS + ln) * 32 + kc8];

    // 2) issue gather loads for cb+1 (units u = t, t+1024) into registers
    if (cb < 7) {
      #pragma unroll
      for (int k = 0; k < 2; ++k) {
        const int u = t + k * 1024;
        const int e = u >> 2, i16 = u & 3;
        const int4 iv = *(const int4*)&tbl_i[e * 4];
        const ushort* base = res2b + (cb + 1) * 32 + i16 * 8;
        cr[k][0] = *(const bf8v*)(base + (size_t)iv.x * 256);
        cr[k][1] = *(const bf8v*)(base + (size_t)iv.y * 256);
        cr[k][2] = *(const bf8v*)(base + (size_t)iv.z * 256);
        cr[k][3] = *(const bf8v*)(base + (size_t)iv.w * 256);
      }
    }

    // 3) MFMA phase on samp[cb&1]
    const ushort* sb = &samp[cb & 1][0];
    __builtin_amdgcn_s_setprio(1);
    #pragma unroll
    for (int tap = 0; tap < 9; ++tap) {
      #pragma unroll
      for (int fp = 0; fp < 4; ++fp) {
        const bf8v af = *(const bf8v*)&sb[(tap * 64 + fp * 16 + ln) * 32 + kc8];
        acc[fp] = __builtin_amdgcn_mfma_f32_16x16x32_bf16(af, bfr[tap], acc[fp], 0, 0, 0);
      }
    }
    __builtin_amdgcn_s_setprio(0);

    // 4) finish cb+1 samples: bilinear combine from regs + ds_write; tail direct
    if (cb < 7) {
      const int buf = (cb + 1) & 1;
      #pragma unroll
      for (int k = 0; k < 2; ++k) {
        const int u = t + k * 1024;
        const int e = u >> 2;
        const float4 gv = *(const float4*)&tbl_w[e * 4];
        bf8v ob;
        #pragma unroll
        for (int jj = 0; jj < 8; ++jj) {
          const float s = gv.x * b2f((ushort)cr[k][0][jj]) + gv.y * b2f((ushort)cr[k][1][jj])
                        + gv.z * b2f((ushort)cr[k][2][jj]) + gv.w * b2f((ushort)cr[k][3][jj]);
          ob[jj] = (short)f2b(s);
        }
        *(bf8v*)&samp[buf][(size_t)u * 8] = ob;
      }
      if (t < 256) {
        const int u = 2048 + t;
        SAMPLE_DIRECT(u, cb + 1, buf)
      }
    }
    __syncthreads();
  }
  #undef SAMPLE_DIRECT

  // epilogue: D row = px, col = o
  #pragma unroll
  for (int fp = 0; fp < 4; ++fp) {
    const f32x4 a = acc[fp];
    const int o = oS + ln;
    const int j0 = fp * 16 + (l >> 4) * 4;
    const size_t base = (((size_t)b * CH + o) * HW + i) * HW + j0;
    const float4 xv = *(const float4*)&x[base];
    float4 r; r.x = a[0] + xv.x; r.y = a[1] + xv.y; r.z = a[2] + xv.z; r.w = a[3] + xv.w;
    *(float4*)&out[base] = r;
  }
}

// ---------------------------------------------------------------------------
extern "C" void kernel_launch(void* const* d_in, const int* in_sizes, int n_in,
                              void* d_out, int out_size, void* d_ws, size_t ws_size,
                              hipStream_t stream) {
  (void)in_sizes; (void)n_in; (void)out_size; (void)ws_size;
  const float* x  = (const float*)d_in[0];
  const float* w1 = (const float*)d_in[1];
  const float* b1 = (const float*)d_in[2];
  const float* w2 = (const float*)d_in[3];
  const float* b2 = (const float*)d_in[4];
  const float* pw = (const float*)d_in[5];
  const float* pb = (const float*)d_in[6];
  const float* dw = (const float*)d_in[7];
  float* out = (float*)d_out;

  char* w = (char*)d_ws;
  size_t off = 0;
  auto carve = [&](size_t bytes) { char* p = w + off; off += (bytes + 255) & ~(size_t)255; return p; };
  ushort* xpad  = (ushort*)carve(8929280);   // 4*4356*256*2 + slack
  ushort* res1  = (ushort*)carve(8929280);
  ushort* res2  = (ushort*)carve(8929280);
  ushort* wpk1  = (ushort*)carve(1179648);
  ushort* wpk2  = (ushort*)carve(1179648);
  ushort* wpkO  = (ushort*)carve(147456);
  ushort* dwpk  = (ushort*)carve(1179648);
  float*  pbias = (float*) carve(256);
  float*  offs  = (float*) carve(2097152);

  zero_borders_k<<<12, 256, 0, stream>>>(xpad, res1, res2);
  pack_w_k<<<900, 256, 0, stream>>>(w1, w2, dw, pw, pb, wpk1, wpk2, dwpk, wpkO, pbias);
  pack_x_k<<<256, 256, 0, stream>>>(x, xpad);
  conv_mfma<256, 0><<<1024, 256, 0, stream>>>(xpad, wpk1, b1, x, res1);
  conv_mfma<256, 1><<<1024, 256, 0, stream>>>(res1, wpk2, b2, nullptr, res2);
  conv_mfma<32, 2><<<256, 256, 0, stream>>>(res2, wpkO, pbias, nullptr, offs);
  deform_mfma<<<NB * HW, 1024, 0, stream>>>(res2, offs, dwpk, x, out);
}